// Round 3
// baseline (885.977 us; speedup 1.0000x reference)
//
#include <hip/hip_runtime.h>

#define NEG_SLOPE 0.2f

// ---- ordered-uint encoding for float atomicMax (zero-init == -inf) ----
static __device__ __forceinline__ unsigned fenc(float f) {
    unsigned u = __float_as_uint(f);
    return (u & 0x80000000u) ? ~u : (u | 0x80000000u);
}
static __device__ __forceinline__ float fdec(unsigned u) {
    return (u & 0x80000000u) ? __uint_as_float(u & 0x7fffffffu) : __uint_as_float(~u);
}

// K1: column sums of edge_attr -> cst[0..16)
__global__ void k_edge_sum(const float* __restrict__ ea, float* __restrict__ cst, int E) {
    float loc[16];
#pragma unroll
    for (int d = 0; d < 16; ++d) loc[d] = 0.f;
    int stride = gridDim.x * blockDim.x;
    for (int e = blockIdx.x * blockDim.x + threadIdx.x; e < E; e += stride) {
#pragma unroll
        for (int d = 0; d < 16; ++d) loc[d] += ea[(size_t)e * 16 + d];
    }
    __shared__ float sh[16];
    if (threadIdx.x < 16) sh[threadIdx.x] = 0.f;
    __syncthreads();
#pragma unroll
    for (int d = 0; d < 16; ++d) atomicAdd(&sh[d], loc[d]);
    __syncthreads();
    if (threadIdx.x < 16) atomicAdd(&cst[threadIdx.x], sh[threadIdx.x]);
}

// K2: finalize e_mean; P1[16][4] at cst[16..80); P2[16] at cst[80..96);
// aloop1[4] at cst[96..100); aloop2 at cst[100]
__global__ void k_prep(const float* __restrict__ We1, const float* __restrict__ ae1,
                       const float* __restrict__ We2, const float* __restrict__ ae2,
                       float* __restrict__ cst, float Ef) {
    int t = threadIdx.x;
    if (t < 16) cst[t] = cst[t] / Ef;
    if (t < 64) {
        int d = t >> 2, h = t & 3;
        float s = 0.f;
        for (int c = 0; c < 32; ++c) s += We1[d * 128 + h * 32 + c] * ae1[h * 32 + c];
        cst[16 + t] = s;                 // P1[d][h] at 16 + d*4 + h
    } else if (t < 80) {
        int d = t - 64;
        float s = 0.f;
        for (int c = 0; c < 32; ++c) s += We2[d * 32 + c] * ae2[c];
        cst[80 + d] = s;
    }
    __threadfence_block();
    __syncthreads();
    if (t < 4) {
        float s = 0.f;
        for (int d = 0; d < 16; ++d) s += cst[d] * cst[16 + d * 4 + t];
        cst[96 + t] = s;
    } else if (t == 4) {
        float s = 0.f;
        for (int d = 0; d < 16; ++d) s += cst[d] * cst[80 + d];
        cst[100] = s;
    }
}

// K3: h1 = x @ W1 (N x 128 @ 128 x 128); fused as1/ad1 per-node reductions.
// 4 rows per block, 128 threads.
__global__ void k_gemm1(const float* __restrict__ x, const float* __restrict__ W1,
                        const float* __restrict__ aS, const float* __restrict__ aD,
                        float* __restrict__ h1, float* __restrict__ as1,
                        float* __restrict__ ad1, int N) {
    __shared__ float xs[4][128];
    __shared__ float red[128];
    const int j = threadIdx.x;
    const int n0 = blockIdx.x * 4;
#pragma unroll
    for (int r = 0; r < 4; ++r) {
        int nn = n0 + r;
        xs[r][j] = (nn < N) ? x[(size_t)nn * 128 + j] : 0.f;
    }
    __syncthreads();
    float acc[4] = {0.f, 0.f, 0.f, 0.f};
    for (int k = 0; k < 128; ++k) {
        float w = W1[k * 128 + j];
        acc[0] += xs[0][k] * w;
        acc[1] += xs[1][k] * w;
        acc[2] += xs[2][k] * w;
        acc[3] += xs[3][k] * w;
    }
    float asw = aS[j], adw = aD[j];
    for (int r = 0; r < 4; ++r) {
        int nn = n0 + r;
        if (nn < N) {
            h1[(size_t)nn * 128 + j] = acc[r];
            red[j] = acc[r] * asw;
            __syncthreads();
            if (j < 4) {
                float s = 0.f;
                for (int c = 0; c < 32; ++c) s += red[j * 32 + c];
                as1[nn * 4 + j] = s;
            }
            __syncthreads();
            red[j] = acc[r] * adw;
            __syncthreads();
            if (j < 4) {
                float s = 0.f;
                for (int c = 0; c < 32; ++c) s += red[j * 32 + c];
                ad1[nn * 4 + j] = s;
            }
            __syncthreads();
        }
    }
}

// K4: layer-1 logits + segment max (one thread per (edge, head))
__global__ void k_logits1(const int* __restrict__ ei, const float* __restrict__ ea,
                          const float* __restrict__ cst, const float* __restrict__ as1,
                          const float* __restrict__ ad1, float* __restrict__ lg,
                          unsigned* __restrict__ menc, int E, int N) {
    int idx = blockIdx.x * blockDim.x + threadIdx.x;
    if (idx >= (E + N) * 4) return;
    int e = idx >> 2, h = idx & 3;
    int s, d;
    float ae;
    if (e < E) {
        s = ei[e];
        d = ei[E + e];
        float sum = 0.f;
#pragma unroll
        for (int t = 0; t < 16; ++t) sum += ea[(size_t)e * 16 + t] * cst[16 + t * 4 + h];
        ae = sum;
    } else {
        s = d = e - E;
        ae = cst[96 + h];
    }
    float v = as1[s * 4 + h] + ad1[d * 4 + h] + ae;
    v = (v > 0.f) ? v : NEG_SLOPE * v;
    lg[idx] = v;
    atomicMax(&menc[d * 4 + h], fenc(v));
}

// K5: exp(logit - max) + segment sum
__global__ void k_exps1(const int* __restrict__ ei, float* __restrict__ lg,
                        const unsigned* __restrict__ menc, float* __restrict__ den,
                        int E, int N) {
    int idx = blockIdx.x * blockDim.x + threadIdx.x;
    if (idx >= (E + N) * 4) return;
    int e = idx >> 2, h = idx & 3;
    int d = (e < E) ? ei[E + e] : e - E;
    float ex = __expf(lg[idx] - fdec(menc[d * 4 + h]));
    lg[idx] = ex;
    atomicAdd(&den[d * 4 + h], ex);
}

// K6: scatter alpha * h1[src] into out1 (one thread per (edge, channel))
__global__ void k_scatter1(const int* __restrict__ ei, const float* __restrict__ lg,
                           const float* __restrict__ den, const float* __restrict__ h1,
                           float* __restrict__ out1, int E, int N) {
    long long idx = (long long)blockIdx.x * blockDim.x + threadIdx.x;
    if (idx >= (long long)(E + N) * 128) return;
    int e = (int)(idx >> 7), c = (int)(idx & 127), h = c >> 5;
    int s, d;
    if (e < E) { s = ei[e]; d = ei[E + e]; }
    else       { s = d = e - E; }
    float alpha = lg[e * 4 + h] / (den[d * 4 + h] + 1e-16f);
    atomicAdd(&out1[(size_t)d * 128 + c], alpha * h1[(size_t)s * 128 + c]);
}

// K7: h2 = relu(out1 + b1) @ W2 (N x 128 @ 128 x 32); fused as2/ad2.
// 8 rows per block, 256 threads (32 lanes per row).
__global__ void k_gemm2(const float* __restrict__ out1, const float* __restrict__ b1,
                        const float* __restrict__ W2, const float* __restrict__ aS,
                        const float* __restrict__ aD, float* __restrict__ h2,
                        float* __restrict__ as2, float* __restrict__ ad2, int N) {
    __shared__ float xs[8][128];
    const int lane = threadIdx.x & 31;
    const int r = threadIdx.x >> 5;
    const int nn = blockIdx.x * 8 + r;
    if (nn < N) {
#pragma unroll
        for (int t = 0; t < 4; ++t) {
            int k = t * 32 + lane;
            xs[r][k] = fmaxf(out1[(size_t)nn * 128 + k] + b1[k], 0.f);
        }
    }
    __syncthreads();
    if (nn < N) {
        float acc = 0.f;
        for (int k = 0; k < 128; ++k) acc += xs[r][k] * W2[k * 32 + lane];
        h2[(size_t)nn * 32 + lane] = acc;
        float vs = acc * aS[lane], vd = acc * aD[lane];
        for (int off = 16; off; off >>= 1) {
            vs += __shfl_down(vs, off, 32);
            vd += __shfl_down(vd, off, 32);
        }
        if (lane == 0) { as2[nn] = vs; ad2[nn] = vd; }
    }
}

// K8: layer-2 logits + segment max (one thread per edge, H=1)
__global__ void k_logits2(const int* __restrict__ ei, const float* __restrict__ ea,
                          const float* __restrict__ cst, const float* __restrict__ as2,
                          const float* __restrict__ ad2, float* __restrict__ lg2,
                          unsigned* __restrict__ m2, int E, int N) {
    int e = blockIdx.x * blockDim.x + threadIdx.x;
    if (e >= E + N) return;
    int s, d;
    float ae;
    if (e < E) {
        s = ei[e];
        d = ei[E + e];
        float sum = 0.f;
#pragma unroll
        for (int t = 0; t < 16; ++t) sum += ea[(size_t)e * 16 + t] * cst[80 + t];
        ae = sum;
    } else {
        s = d = e - E;
        ae = cst[100];
    }
    float v = as2[s] + ad2[d] + ae;
    v = (v > 0.f) ? v : NEG_SLOPE * v;
    lg2[e] = v;
    atomicMax(&m2[d], fenc(v));
}

__global__ void k_exps2(const int* __restrict__ ei, float* __restrict__ lg2,
                        const unsigned* __restrict__ m2, float* __restrict__ den2,
                        int E, int N) {
    int e = blockIdx.x * blockDim.x + threadIdx.x;
    if (e >= E + N) return;
    int d = (e < E) ? ei[E + e] : e - E;
    float ex = __expf(lg2[e] - fdec(m2[d]));
    lg2[e] = ex;
    atomicAdd(&den2[d], ex);
}

// K10: scatter alpha * h2[src] into out (one thread per (edge, channel))
__global__ void k_scatter2(const int* __restrict__ ei, const float* __restrict__ lg2,
                           const float* __restrict__ den2, const float* __restrict__ h2,
                           float* __restrict__ out, int E, int N) {
    long long idx = (long long)blockIdx.x * blockDim.x + threadIdx.x;
    if (idx >= (long long)(E + N) * 32) return;
    int e = (int)(idx >> 5), c = (int)(idx & 31);
    int s, d;
    if (e < E) { s = ei[e]; d = ei[E + e]; }
    else       { s = d = e - E; }
    float alpha = lg2[e] / (den2[d] + 1e-16f);
    atomicAdd(&out[(size_t)d * 32 + c], alpha * h2[(size_t)s * 32 + c]);
}

__global__ void k_bias2(float* __restrict__ out, const float* __restrict__ b2, int N) {
    int idx = blockIdx.x * blockDim.x + threadIdx.x;
    if (idx < N * 32) out[idx] += b2[idx & 31];
}

extern "C" void kernel_launch(void* const* d_in, const int* in_sizes, int n_in,
                              void* d_out, int out_size, void* d_ws, size_t ws_size,
                              hipStream_t stream) {
    const float* x    = (const float*)d_in[0];
    const int*   ei   = (const int*)d_in[1];
    const float* ea   = (const float*)d_in[2];
    const float* W1   = (const float*)d_in[3];
    const float* We1  = (const float*)d_in[4];
    const float* as1w = (const float*)d_in[5];
    const float* ad1w = (const float*)d_in[6];
    const float* ae1w = (const float*)d_in[7];
    const float* b1   = (const float*)d_in[8];
    const float* W2   = (const float*)d_in[9];
    const float* We2  = (const float*)d_in[10];
    const float* as2w = (const float*)d_in[11];
    const float* ad2w = (const float*)d_in[12];
    const float* ae2w = (const float*)d_in[13];
    const float* b2   = (const float*)d_in[14];

    const int N  = in_sizes[0] / 128;
    const int E  = in_sizes[2] / 16;
    const int E2 = E + N;

    float* ws = (float*)d_ws;
    size_t o = 0;
    float* cst  = ws;       o += 128;
    float* h1   = ws + o;   o += (size_t)N * 128;   // layer-2 buffers overlay this later
    float* out1 = ws + o;   o += (size_t)N * 128;
    float* lg1  = ws + o;   o += (size_t)E2 * 4;
    float* as1  = ws + o;   o += (size_t)N * 4;
    float* ad1  = ws + o;   o += (size_t)N * 4;
    unsigned* m1 = (unsigned*)(ws + o); o += (size_t)N * 4;
    float* den1 = ws + o;   o += (size_t)N * 4;
    // overlay layer 2 onto h1 region (dead after scatter1): need N*32+N+N+E2+N+N floats <= N*128
    float* h2   = h1;
    float* as2  = h2 + (size_t)N * 32;
    float* ad2  = as2 + N;
    float* lg2  = ad2 + N;
    unsigned* m2 = (unsigned*)(lg2 + E2);
    float* den2 = (float*)m2 + N;

    // zero init: cst, out1, m1+den1 (contiguous), d_out
    hipMemsetAsync(cst, 0, 128 * sizeof(float), stream);
    hipMemsetAsync(out1, 0, (size_t)N * 128 * sizeof(float), stream);
    hipMemsetAsync(m1, 0, (size_t)N * 8 * sizeof(float), stream);
    hipMemsetAsync(d_out, 0, (size_t)out_size * sizeof(float), stream);

    k_edge_sum<<<256, 256, 0, stream>>>(ea, cst, E);
    k_prep<<<1, 128, 0, stream>>>(We1, ae1w, We2, ae2w, cst, (float)E);
    k_gemm1<<<(N + 3) / 4, 128, 0, stream>>>(x, W1, as1w, ad1w, h1, as1, ad1, N);

    int tot1 = E2 * 4;
    k_logits1<<<(tot1 + 255) / 256, 256, 0, stream>>>(ei, ea, cst, as1, ad1, lg1, m1, E, N);
    k_exps1<<<(tot1 + 255) / 256, 256, 0, stream>>>(ei, lg1, m1, den1, E, N);
    long long tots1 = (long long)E2 * 128;
    k_scatter1<<<(int)((tots1 + 255) / 256), 256, 0, stream>>>(ei, lg1, den1, h1, out1, E, N);

    // zero m2+den2 (overlaid region was used during layer 1)
    hipMemsetAsync(m2, 0, (size_t)N * 2 * sizeof(float), stream);

    k_gemm2<<<(N + 7) / 8, 256, 0, stream>>>(out1, b1, W2, as2w, ad2w, h2, as2, ad2, N);
    k_logits2<<<(E2 + 255) / 256, 256, 0, stream>>>(ei, ea, cst, as2, ad2, lg2, m2, E, N);
    k_exps2<<<(E2 + 255) / 256, 256, 0, stream>>>(ei, lg2, m2, den2, E, N);
    long long tots2 = (long long)E2 * 32;
    k_scatter2<<<(int)((tots2 + 255) / 256), 256, 0, stream>>>(ei, lg2, den2, h2, (float*)d_out, E, N);
    k_bias2<<<(N * 32 + 255) / 256, 256, 0, stream>>>((float*)d_out, b2, N);
}

// Round 5
// 706.913 us; speedup vs baseline: 1.2533x; 1.2533x over previous
//
#include <hip/hip_runtime.h>

#define NEG_SLOPE 0.2f

// ---- ordered-uint encoding for float atomicMax (zero-init == -inf) ----
static __device__ __forceinline__ unsigned fenc(float f) {
    unsigned u = __float_as_uint(f);
    return (u & 0x80000000u) ? ~u : (u | 0x80000000u);
}
static __device__ __forceinline__ float fdec(unsigned u) {
    return (u & 0x80000000u) ? __uint_as_float(u & 0x7fffffffu) : __uint_as_float(~u);
}

// K1: column sums of edge_attr -> cst[0..16)
__global__ void k_edge_sum(const float* __restrict__ ea, float* __restrict__ cst, int E) {
    float loc[16];
#pragma unroll
    for (int d = 0; d < 16; ++d) loc[d] = 0.f;
    int stride = gridDim.x * blockDim.x;
    for (int e = blockIdx.x * blockDim.x + threadIdx.x; e < E; e += stride) {
#pragma unroll
        for (int d = 0; d < 16; ++d) loc[d] += ea[(size_t)e * 16 + d];
    }
    __shared__ float sh[16];
    if (threadIdx.x < 16) sh[threadIdx.x] = 0.f;
    __syncthreads();
#pragma unroll
    for (int d = 0; d < 16; ++d) atomicAdd(&sh[d], loc[d]);
    __syncthreads();
    if (threadIdx.x < 16) atomicAdd(&cst[threadIdx.x], sh[threadIdx.x]);
}

// K2: finalize e_mean; P1[16][4] at cst[16..80); P2[16] at cst[80..96);
// aloop1[4] at cst[96..100); aloop2 at cst[100]
__global__ void k_prep(const float* __restrict__ We1, const float* __restrict__ ae1,
                       const float* __restrict__ We2, const float* __restrict__ ae2,
                       float* __restrict__ cst, float Ef) {
    int t = threadIdx.x;
    if (t < 16) cst[t] = cst[t] / Ef;
    if (t < 64) {
        int d = t >> 2, h = t & 3;
        float s = 0.f;
        for (int c = 0; c < 32; ++c) s += We1[d * 128 + h * 32 + c] * ae1[h * 32 + c];
        cst[16 + t] = s;
    } else if (t < 80) {
        int d = t - 64;
        float s = 0.f;
        for (int c = 0; c < 32; ++c) s += We2[d * 32 + c] * ae2[c];
        cst[80 + d] = s;
    }
    __threadfence_block();
    __syncthreads();
    if (t < 4) {
        float s = 0.f;
        for (int d = 0; d < 16; ++d) s += cst[d] * cst[16 + d * 4 + t];
        cst[96 + t] = s;
    } else if (t == 4) {
        float s = 0.f;
        for (int d = 0; d < 16; ++d) s += cst[d] * cst[80 + d];
        cst[100] = s;
    }
}

// ---- CSR build ----
// deg histogram over dst (incl. self-loops). cursor doubles as deg array.
__global__ void k_deg(const int* __restrict__ ei, int* __restrict__ cursor, int E, int N) {
    int e = blockIdx.x * blockDim.x + threadIdx.x;
    if (e >= E + N) return;
    int d = (e < E) ? ei[E + e] : e - E;
    atomicAdd(&cursor[d], 1);
}

// single-block exclusive prefix scan; cursor (=deg in) -> rowptr + cursor (excl offsets out)
__global__ void k_scan(int* __restrict__ cursor, int* __restrict__ rowptr, int N) {
    __shared__ int sh[1024];
    const int t = threadIdx.x;
    int carry = 0;
    for (int base = 0; base < N; base += 1024) {
        int i = base + t;
        int v = (i < N) ? cursor[i] : 0;
        sh[t] = v;
        __syncthreads();
        for (int off = 1; off < 1024; off <<= 1) {
            int add = (t >= off) ? sh[t - off] : 0;
            __syncthreads();
            sh[t] += add;
            __syncthreads();
        }
        int excl = sh[t] - v;
        if (i < N) { rowptr[i] = carry + excl; cursor[i] = carry + excl; }
        int total = sh[1023];
        __syncthreads();   // protect sh[1023] read before next chunk overwrites
        carry += total;
    }
    if (t == 0) rowptr[N] = carry;
}

__global__ void k_fill(const int* __restrict__ ei, int* __restrict__ cursor,
                       int* __restrict__ csr_src, int* __restrict__ csr_eid, int E, int N) {
    int e = blockIdx.x * blockDim.x + threadIdx.x;
    if (e >= E + N) return;
    int s, d;
    if (e < E) { s = ei[e]; d = ei[E + e]; }
    else       { s = d = e - E; }
    int pos = atomicAdd(&cursor[d], 1);
    csr_src[pos] = s;
    csr_eid[pos] = e;
}

// K3: h1 = x @ W1 (N x 128 @ 128 x 128); fused as1/ad1 per-node reductions.
__global__ void k_gemm1(const float* __restrict__ x, const float* __restrict__ W1,
                        const float* __restrict__ aS, const float* __restrict__ aD,
                        float* __restrict__ h1, float* __restrict__ as1,
                        float* __restrict__ ad1, int N) {
    __shared__ float xs[4][128];
    __shared__ float red[128];
    const int j = threadIdx.x;
    const int n0 = blockIdx.x * 4;
#pragma unroll
    for (int r = 0; r < 4; ++r) {
        int nn = n0 + r;
        xs[r][j] = (nn < N) ? x[(size_t)nn * 128 + j] : 0.f;
    }
    __syncthreads();
    float acc[4] = {0.f, 0.f, 0.f, 0.f};
    for (int k = 0; k < 128; ++k) {
        float w = W1[k * 128 + j];
        acc[0] += xs[0][k] * w;
        acc[1] += xs[1][k] * w;
        acc[2] += xs[2][k] * w;
        acc[3] += xs[3][k] * w;
    }
    float asw = aS[j], adw = aD[j];
    for (int r = 0; r < 4; ++r) {
        int nn = n0 + r;
        if (nn < N) {
            h1[(size_t)nn * 128 + j] = acc[r];
            red[j] = acc[r] * asw;
            __syncthreads();
            if (j < 4) {
                float s = 0.f;
                for (int c = 0; c < 32; ++c) s += red[j * 32 + c];
                as1[nn * 4 + j] = s;
            }
            __syncthreads();
            red[j] = acc[r] * adw;
            __syncthreads();
            if (j < 4) {
                float s = 0.f;
                for (int c = 0; c < 32; ++c) s += red[j * 32 + c];
                ad1[nn * 4 + j] = s;
            }
            __syncthreads();
        }
    }
}

// K4: layer-1 logits + segment max (one thread per (edge, head))
__global__ void k_logits1(const int* __restrict__ ei, const float* __restrict__ ea,
                          const float* __restrict__ cst, const float* __restrict__ as1,
                          const float* __restrict__ ad1, float* __restrict__ lg,
                          unsigned* __restrict__ menc, int E, int N) {
    int idx = blockIdx.x * blockDim.x + threadIdx.x;
    if (idx >= (E + N) * 4) return;
    int e = idx >> 2, h = idx & 3;
    int s, d;
    float ae;
    if (e < E) {
        s = ei[e];
        d = ei[E + e];
        float sum = 0.f;
#pragma unroll
        for (int t = 0; t < 16; ++t) sum += ea[(size_t)e * 16 + t] * cst[16 + t * 4 + h];
        ae = sum;
    } else {
        s = d = e - E;
        ae = cst[96 + h];
    }
    float v = as1[s * 4 + h] + ad1[d * 4 + h] + ae;
    v = (v > 0.f) ? v : NEG_SLOPE * v;
    lg[idx] = v;
    atomicMax(&menc[d * 4 + h], fenc(v));
}

// K5: exp(logit - max) + segment sum
__global__ void k_exps1(const int* __restrict__ ei, float* __restrict__ lg,
                        const unsigned* __restrict__ menc, float* __restrict__ den,
                        int E, int N) {
    int idx = blockIdx.x * blockDim.x + threadIdx.x;
    if (idx >= (E + N) * 4) return;
    int e = idx >> 2, h = idx & 3;
    int d = (e < E) ? ei[E + e] : e - E;
    float ex = __expf(lg[idx] - fdec(menc[d * 4 + h]));
    lg[idx] = ex;
    atomicAdd(&den[d * 4 + h], ex);
}

// K6: CSR aggregation layer 1 — one wave per dst row, lane owns channels 2l,2l+1.
__global__ void k_aggr1(const int* __restrict__ rowptr, const int* __restrict__ csr_src,
                        const int* __restrict__ csr_eid, const float* __restrict__ lg1,
                        const float* __restrict__ den1, const float* __restrict__ h1,
                        float* __restrict__ out1, int N) {
    int wid = (blockIdx.x * blockDim.x + threadIdx.x) >> 6;
    int lane = threadIdx.x & 63;
    if (wid >= N) return;
    const int h = lane >> 4;                    // head of channels 2l,2l+1
    const int start = rowptr[wid], end = rowptr[wid + 1];
    const float inv = 1.f / (den1[wid * 4 + h] + 1e-16f);
    float ax = 0.f, ay = 0.f;
    int i = start;
    for (; i + 1 < end; i += 2) {
        int s0 = csr_src[i],     e0 = csr_eid[i];
        int s1 = csr_src[i + 1], e1 = csr_eid[i + 1];
        float ex0 = lg1[e0 * 4 + h];
        float ex1 = lg1[e1 * 4 + h];
        float2 v0 = *(const float2*)&h1[(size_t)s0 * 128 + 2 * lane];
        float2 v1 = *(const float2*)&h1[(size_t)s1 * 128 + 2 * lane];
        ax += ex0 * v0.x + ex1 * v1.x;
        ay += ex0 * v0.y + ex1 * v1.y;
    }
    if (i < end) {
        int s0 = csr_src[i], e0 = csr_eid[i];
        float ex0 = lg1[e0 * 4 + h];
        float2 v0 = *(const float2*)&h1[(size_t)s0 * 128 + 2 * lane];
        ax += ex0 * v0.x;
        ay += ex0 * v0.y;
    }
    float2 r; r.x = ax * inv; r.y = ay * inv;
    *(float2*)&out1[(size_t)wid * 128 + 2 * lane] = r;
}

// K7: h2 = relu(out1 + b1) @ W2 (N x 128 @ 128 x 32); fused as2/ad2.
__global__ void k_gemm2(const float* __restrict__ out1, const float* __restrict__ b1,
                        const float* __restrict__ W2, const float* __restrict__ aS,
                        const float* __restrict__ aD, float* __restrict__ h2,
                        float* __restrict__ as2, float* __restrict__ ad2, int N) {
    __shared__ float xs[8][128];
    const int lane = threadIdx.x & 31;
    const int r = threadIdx.x >> 5;
    const int nn = blockIdx.x * 8 + r;
    if (nn < N) {
#pragma unroll
        for (int t = 0; t < 4; ++t) {
            int k = t * 32 + lane;
            xs[r][k] = fmaxf(out1[(size_t)nn * 128 + k] + b1[k], 0.f);
        }
    }
    __syncthreads();
    if (nn < N) {
        float acc = 0.f;
        for (int k = 0; k < 128; ++k) acc += xs[r][k] * W2[k * 32 + lane];
        h2[(size_t)nn * 32 + lane] = acc;
        float vs = acc * aS[lane], vd = acc * aD[lane];
        for (int off = 16; off; off >>= 1) {
            vs += __shfl_down(vs, off, 32);
            vd += __shfl_down(vd, off, 32);
        }
        if (lane == 0) { as2[nn] = vs; ad2[nn] = vd; }
    }
}

// K8: layer-2 logits + segment max (one thread per edge, H=1)
__global__ void k_logits2(const int* __restrict__ ei, const float* __restrict__ ea,
                          const float* __restrict__ cst, const float* __restrict__ as2,
                          const float* __restrict__ ad2, float* __restrict__ lg2,
                          unsigned* __restrict__ m2, int E, int N) {
    int e = blockIdx.x * blockDim.x + threadIdx.x;
    if (e >= E + N) return;
    int s, d;
    float ae;
    if (e < E) {
        s = ei[e];
        d = ei[E + e];
        float sum = 0.f;
#pragma unroll
        for (int t = 0; t < 16; ++t) sum += ea[(size_t)e * 16 + t] * cst[80 + t];
        ae = sum;
    } else {
        s = d = e - E;
        ae = cst[100];
    }
    float v = as2[s] + ad2[d] + ae;
    v = (v > 0.f) ? v : NEG_SLOPE * v;
    lg2[e] = v;
    atomicMax(&m2[d], fenc(v));
}

__global__ void k_exps2(const int* __restrict__ ei, float* __restrict__ lg2,
                        const unsigned* __restrict__ m2, float* __restrict__ den2,
                        int E, int N) {
    int e = blockIdx.x * blockDim.x + threadIdx.x;
    if (e >= E + N) return;
    int d = (e < E) ? ei[E + e] : e - E;
    float ex = __expf(lg2[e] - fdec(m2[d]));
    lg2[e] = ex;
    atomicAdd(&den2[d], ex);
}

// K10: CSR aggregation layer 2 + bias — one wave per dst row; halves of the
// wave process even/odd edges, lanes<32 own the 32 channels.
__global__ void k_aggr2(const int* __restrict__ rowptr, const int* __restrict__ csr_src,
                        const int* __restrict__ csr_eid, const float* __restrict__ lg2,
                        const float* __restrict__ den2, const float* __restrict__ h2,
                        const float* __restrict__ b2, float* __restrict__ out, int N) {
    int wid = (blockIdx.x * blockDim.x + threadIdx.x) >> 6;
    int lane = threadIdx.x & 63;
    if (wid >= N) return;
    const int c = lane & 31;
    const int half = lane >> 5;
    const int start = rowptr[wid], end = rowptr[wid + 1];
    float acc = 0.f;
    for (int i = start + half; i < end; i += 2) {
        int s = csr_src[i], e = csr_eid[i];
        acc += lg2[e] * h2[(size_t)s * 32 + c];
    }
    acc += __shfl_down(acc, 32, 64);
    if (half == 0) {
        float inv = 1.f / (den2[wid] + 1e-16f);
        out[(size_t)wid * 32 + c] = acc * inv + b2[c];
    }
}

extern "C" void kernel_launch(void* const* d_in, const int* in_sizes, int n_in,
                              void* d_out, int out_size, void* d_ws, size_t ws_size,
                              hipStream_t stream) {
    const float* x    = (const float*)d_in[0];
    const int*   ei   = (const int*)d_in[1];
    const float* ea   = (const float*)d_in[2];
    const float* W1   = (const float*)d_in[3];
    const float* We1  = (const float*)d_in[4];
    const float* as1w = (const float*)d_in[5];
    const float* ad1w = (const float*)d_in[6];
    const float* ae1w = (const float*)d_in[7];
    const float* b1   = (const float*)d_in[8];
    const float* W2   = (const float*)d_in[9];
    const float* We2  = (const float*)d_in[10];
    const float* as2w = (const float*)d_in[11];
    const float* ad2w = (const float*)d_in[12];
    const float* ae2w = (const float*)d_in[13];
    const float* b2   = (const float*)d_in[14];

    const int N  = in_sizes[0] / 128;
    const int E  = in_sizes[2] / 16;
    const int E2 = E + N;

    float* ws = (float*)d_ws;
    size_t o = 0;
    float* cst  = ws;       o += 128;
    float* h1   = ws + o;   o += (size_t)N * 128;   // layer-2 buffers overlay this later
    float* out1 = ws + o;   o += (size_t)N * 128;
    float* lg1  = ws + o;   o += (size_t)E2 * 4;
    float* as1  = ws + o;   o += (size_t)N * 4;
    float* ad1  = ws + o;   o += (size_t)N * 4;
    unsigned* m1 = (unsigned*)(ws + o); o += (size_t)N * 4;
    float* den1 = ws + o;   o += (size_t)N * 4;
    int* rowptr = (int*)(ws + o);  o += (size_t)N + 1;
    int* cursor = (int*)(ws + o);  o += (size_t)N;       // also deg
    int* csr_src = (int*)(ws + o); o += (size_t)E2;
    int* csr_eid = (int*)(ws + o); o += (size_t)E2;
    // overlay layer 2 onto h1 region (dead after gemm2 consumes out1)
    float* h2   = h1;
    float* as2  = h2 + (size_t)N * 32;
    float* ad2  = as2 + N;
    float* lg2  = ad2 + N;
    unsigned* m2 = (unsigned*)(lg2 + E2);
    float* den2 = (float*)m2 + N;

    // zero init: cst, m1+den1 (contiguous), cursor
    hipMemsetAsync(cst, 0, 128 * sizeof(float), stream);
    hipMemsetAsync(m1, 0, (size_t)N * 8 * sizeof(float), stream);
    hipMemsetAsync(cursor, 0, (size_t)N * sizeof(int), stream);

    // CSR build (independent of feature pipeline)
    k_deg<<<(E2 + 255) / 256, 256, 0, stream>>>(ei, cursor, E, N);
    k_scan<<<1, 1024, 0, stream>>>(cursor, rowptr, N);
    k_fill<<<(E2 + 255) / 256, 256, 0, stream>>>(ei, cursor, csr_src, csr_eid, E, N);

    k_edge_sum<<<256, 256, 0, stream>>>(ea, cst, E);
    k_prep<<<1, 128, 0, stream>>>(We1, ae1w, We2, ae2w, cst, (float)E);
    k_gemm1<<<(N + 3) / 4, 128, 0, stream>>>(x, W1, as1w, ad1w, h1, as1, ad1, N);

    int tot1 = E2 * 4;
    k_logits1<<<(tot1 + 255) / 256, 256, 0, stream>>>(ei, ea, cst, as1, ad1, lg1, m1, E, N);
    k_exps1<<<(tot1 + 255) / 256, 256, 0, stream>>>(ei, lg1, m1, den1, E, N);
    k_aggr1<<<(N + 3) / 4, 256, 0, stream>>>(rowptr, csr_src, csr_eid, lg1, den1, h1, out1, N);

    // zero m2+den2 (overlaid region was used during layer 1)
    hipMemsetAsync(m2, 0, (size_t)N * 2 * sizeof(float), stream);

    k_gemm2<<<(N + 7) / 8, 256, 0, stream>>>(out1, b1, W2, as2w, ad2w, h2, as2, ad2, N);
    k_logits2<<<(E2 + 255) / 256, 256, 0, stream>>>(ei, ea, cst, as2, ad2, lg2, m2, E, N);
    k_exps2<<<(E2 + 255) / 256, 256, 0, stream>>>(ei, lg2, m2, den2, E, N);
    k_aggr2<<<(N + 3) / 4, 256, 0, stream>>>(rowptr, csr_src, csr_eid, lg2, den2, h2, b2, (float*)d_out, N);
}

// Round 6
// 630.302 us; speedup vs baseline: 1.4056x; 1.1215x over previous
//
#include <hip/hip_runtime.h>

#define NEG_SLOPE 0.2f

// ---- ordered-uint encoding for float atomicMax (zero-init == -inf) ----
static __device__ __forceinline__ unsigned fenc(float f) {
    unsigned u = __float_as_uint(f);
    return (u & 0x80000000u) ? ~u : (u | 0x80000000u);
}
static __device__ __forceinline__ float fdec(unsigned u) {
    return (u & 0x80000000u) ? __uint_as_float(u & 0x7fffffffu) : __uint_as_float(~u);
}

// K1: column sums of edge_attr -> cst[0..16)
__global__ void k_edge_sum(const float* __restrict__ ea, float* __restrict__ cst, int E) {
    float loc[16];
#pragma unroll
    for (int d = 0; d < 16; ++d) loc[d] = 0.f;
    int stride = gridDim.x * blockDim.x;
    for (int e = blockIdx.x * blockDim.x + threadIdx.x; e < E; e += stride) {
#pragma unroll
        for (int d = 0; d < 16; ++d) loc[d] += ea[(size_t)e * 16 + d];
    }
    __shared__ float sh[16];
    if (threadIdx.x < 16) sh[threadIdx.x] = 0.f;
    __syncthreads();
#pragma unroll
    for (int d = 0; d < 16; ++d) atomicAdd(&sh[d], loc[d]);
    __syncthreads();
    if (threadIdx.x < 16) atomicAdd(&cst[threadIdx.x], sh[threadIdx.x]);
}

// K2: finalize e_mean; P1[16][4] at cst[16..80); P2[16] at cst[80..96);
// aloop1[4] at cst[96..100); aloop2 at cst[100]
__global__ void k_prep(const float* __restrict__ We1, const float* __restrict__ ae1,
                       const float* __restrict__ We2, const float* __restrict__ ae2,
                       float* __restrict__ cst, float Ef) {
    int t = threadIdx.x;
    if (t < 16) cst[t] = cst[t] / Ef;
    if (t < 64) {
        int d = t >> 2, h = t & 3;
        float s = 0.f;
        for (int c = 0; c < 32; ++c) s += We1[d * 128 + h * 32 + c] * ae1[h * 32 + c];
        cst[16 + t] = s;
    } else if (t < 80) {
        int d = t - 64;
        float s = 0.f;
        for (int c = 0; c < 32; ++c) s += We2[d * 32 + c] * ae2[c];
        cst[80 + d] = s;
    }
    __threadfence_block();
    __syncthreads();
    if (t < 4) {
        float s = 0.f;
        for (int d = 0; d < 16; ++d) s += cst[d] * cst[16 + d * 4 + t];
        cst[96 + t] = s;
    } else if (t == 4) {
        float s = 0.f;
        for (int d = 0; d < 16; ++d) s += cst[d] * cst[80 + d];
        cst[100] = s;
    }
}

// ---- CSR build ----
// deg histogram over dst (incl. self-loops). cursor doubles as deg array.
__global__ void k_deg(const int* __restrict__ ei, int* __restrict__ cursor, int E, int N) {
    int e = blockIdx.x * blockDim.x + threadIdx.x;
    if (e >= E + N) return;
    int d = (e < E) ? ei[E + e] : e - E;
    atomicAdd(&cursor[d], 1);
}

// ---- hierarchical prefix scan (3 phases, replaces single-block serial scan) ----
// phase 1: each block scans a 1024-chunk of deg; writes local EXCLUSIVE scan
// to excl and the chunk total to bsum[blockIdx].
__global__ void k_scan1(const int* __restrict__ deg, int* __restrict__ excl,
                        int* __restrict__ bsum, int N) {
    __shared__ int sh[1024];
    const int t = threadIdx.x;
    const int i = blockIdx.x * 1024 + t;
    int v = (i < N) ? deg[i] : 0;
    sh[t] = v;
    __syncthreads();
    for (int off = 1; off < 1024; off <<= 1) {
        int add = (t >= off) ? sh[t - off] : 0;
        __syncthreads();
        sh[t] += add;
        __syncthreads();
    }
    if (i < N) excl[i] = sh[t] - v;
    if (t == 1023) bsum[blockIdx.x] = sh[1023];
}

// phase 2: single block exclusive-scans bsum (nb <= 1024)
__global__ void k_scan2(int* __restrict__ bsum, int nb) {
    __shared__ int sh[1024];
    const int t = threadIdx.x;
    int v = (t < nb) ? bsum[t] : 0;
    sh[t] = v;
    __syncthreads();
    for (int off = 1; off < 1024; off <<= 1) {
        int add = (t >= off) ? sh[t - off] : 0;
        __syncthreads();
        sh[t] += add;
        __syncthreads();
    }
    if (t < nb) bsum[t] = sh[t] - v;   // exclusive
}

// phase 3: rowptr[i] = cursor[i] = excl[i] + bsum[i>>10]; rowptr[N] = E2 (static)
__global__ void k_scan3(const int* __restrict__ excl, const int* __restrict__ bsum,
                        int* __restrict__ rowptr, int* __restrict__ cursor,
                        int N, int E2) {
    int i = blockIdx.x * blockDim.x + threadIdx.x;
    if (i < N) {
        int r = excl[i] + bsum[i >> 10];
        rowptr[i] = r;
        cursor[i] = r;
    }
    if (i == 0) rowptr[N] = E2;
}

__global__ void k_fill(const int* __restrict__ ei, int* __restrict__ cursor,
                       int* __restrict__ csr_src, int* __restrict__ csr_eid, int E, int N) {
    int e = blockIdx.x * blockDim.x + threadIdx.x;
    if (e >= E + N) return;
    int s, d;
    if (e < E) { s = ei[e]; d = ei[E + e]; }
    else       { s = d = e - E; }
    int pos = atomicAdd(&cursor[d], 1);
    csr_src[pos] = s;
    csr_eid[pos] = e;
}

// K3: h1 = x @ W1 (N x 128 @ 128 x 128); fused as1/ad1 per-node reductions.
__global__ void k_gemm1(const float* __restrict__ x, const float* __restrict__ W1,
                        const float* __restrict__ aS, const float* __restrict__ aD,
                        float* __restrict__ h1, float* __restrict__ as1,
                        float* __restrict__ ad1, int N) {
    __shared__ float xs[4][128];
    __shared__ float red[128];
    const int j = threadIdx.x;
    const int n0 = blockIdx.x * 4;
#pragma unroll
    for (int r = 0; r < 4; ++r) {
        int nn = n0 + r;
        xs[r][j] = (nn < N) ? x[(size_t)nn * 128 + j] : 0.f;
    }
    __syncthreads();
    float acc[4] = {0.f, 0.f, 0.f, 0.f};
    for (int k = 0; k < 128; ++k) {
        float w = W1[k * 128 + j];
        acc[0] += xs[0][k] * w;
        acc[1] += xs[1][k] * w;
        acc[2] += xs[2][k] * w;
        acc[3] += xs[3][k] * w;
    }
    float asw = aS[j], adw = aD[j];
    for (int r = 0; r < 4; ++r) {
        int nn = n0 + r;
        if (nn < N) {
            h1[(size_t)nn * 128 + j] = acc[r];
            red[j] = acc[r] * asw;
            __syncthreads();
            if (j < 4) {
                float s = 0.f;
                for (int c = 0; c < 32; ++c) s += red[j * 32 + c];
                as1[nn * 4 + j] = s;
            }
            __syncthreads();
            red[j] = acc[r] * adw;
            __syncthreads();
            if (j < 4) {
                float s = 0.f;
                for (int c = 0; c < 32; ++c) s += red[j * 32 + c];
                ad1[nn * 4 + j] = s;
            }
            __syncthreads();
        }
    }
}

// K4: layer-1 logits + segment max (one thread per (edge, head))
__global__ void k_logits1(const int* __restrict__ ei, const float* __restrict__ ea,
                          const float* __restrict__ cst, const float* __restrict__ as1,
                          const float* __restrict__ ad1, float* __restrict__ lg,
                          unsigned* __restrict__ menc, int E, int N) {
    int idx = blockIdx.x * blockDim.x + threadIdx.x;
    if (idx >= (E + N) * 4) return;
    int e = idx >> 2, h = idx & 3;
    int s, d;
    float ae;
    if (e < E) {
        s = ei[e];
        d = ei[E + e];
        float sum = 0.f;
#pragma unroll
        for (int t = 0; t < 16; ++t) sum += ea[(size_t)e * 16 + t] * cst[16 + t * 4 + h];
        ae = sum;
    } else {
        s = d = e - E;
        ae = cst[96 + h];
    }
    float v = as1[s * 4 + h] + ad1[d * 4 + h] + ae;
    v = (v > 0.f) ? v : NEG_SLOPE * v;
    lg[idx] = v;
    atomicMax(&menc[d * 4 + h], fenc(v));
}

// K5: exp(logit - max) + segment sum
__global__ void k_exps1(const int* __restrict__ ei, float* __restrict__ lg,
                        const unsigned* __restrict__ menc, float* __restrict__ den,
                        int E, int N) {
    int idx = blockIdx.x * blockDim.x + threadIdx.x;
    if (idx >= (E + N) * 4) return;
    int e = idx >> 2, h = idx & 3;
    int d = (e < E) ? ei[E + e] : e - E;
    float ex = __expf(lg[idx] - fdec(menc[d * 4 + h]));
    lg[idx] = ex;
    atomicAdd(&den[d * 4 + h], ex);
}

// K6: CSR aggregation layer 1 — one wave per dst row, lane owns channels 2l,2l+1.
__global__ void k_aggr1(const int* __restrict__ rowptr, const int* __restrict__ csr_src,
                        const int* __restrict__ csr_eid, const float* __restrict__ lg1,
                        const float* __restrict__ den1, const float* __restrict__ h1,
                        float* __restrict__ out1, int N) {
    int wid = (blockIdx.x * blockDim.x + threadIdx.x) >> 6;
    int lane = threadIdx.x & 63;
    if (wid >= N) return;
    const int h = lane >> 4;                    // head of channels 2l,2l+1
    const int start = rowptr[wid], end = rowptr[wid + 1];
    const float inv = 1.f / (den1[wid * 4 + h] + 1e-16f);
    float ax = 0.f, ay = 0.f;
    int i = start;
    for (; i + 1 < end; i += 2) {
        int s0 = csr_src[i],     e0 = csr_eid[i];
        int s1 = csr_src[i + 1], e1 = csr_eid[i + 1];
        float ex0 = lg1[e0 * 4 + h];
        float ex1 = lg1[e1 * 4 + h];
        float2 v0 = *(const float2*)&h1[(size_t)s0 * 128 + 2 * lane];
        float2 v1 = *(const float2*)&h1[(size_t)s1 * 128 + 2 * lane];
        ax += ex0 * v0.x + ex1 * v1.x;
        ay += ex0 * v0.y + ex1 * v1.y;
    }
    if (i < end) {
        int s0 = csr_src[i], e0 = csr_eid[i];
        float ex0 = lg1[e0 * 4 + h];
        float2 v0 = *(const float2*)&h1[(size_t)s0 * 128 + 2 * lane];
        ax += ex0 * v0.x;
        ay += ex0 * v0.y;
    }
    float2 r; r.x = ax * inv; r.y = ay * inv;
    *(float2*)&out1[(size_t)wid * 128 + 2 * lane] = r;
}

// K7: h2 = relu(out1 + b1) @ W2 (N x 128 @ 128 x 32); fused as2/ad2.
__global__ void k_gemm2(const float* __restrict__ out1, const float* __restrict__ b1,
                        const float* __restrict__ W2, const float* __restrict__ aS,
                        const float* __restrict__ aD, float* __restrict__ h2,
                        float* __restrict__ as2, float* __restrict__ ad2, int N) {
    __shared__ float xs[8][128];
    const int lane = threadIdx.x & 31;
    const int r = threadIdx.x >> 5;
    const int nn = blockIdx.x * 8 + r;
    if (nn < N) {
#pragma unroll
        for (int t = 0; t < 4; ++t) {
            int k = t * 32 + lane;
            xs[r][k] = fmaxf(out1[(size_t)nn * 128 + k] + b1[k], 0.f);
        }
    }
    __syncthreads();
    if (nn < N) {
        float acc = 0.f;
        for (int k = 0; k < 128; ++k) acc += xs[r][k] * W2[k * 32 + lane];
        h2[(size_t)nn * 32 + lane] = acc;
        float vs = acc * aS[lane], vd = acc * aD[lane];
        for (int off = 16; off; off >>= 1) {
            vs += __shfl_down(vs, off, 32);
            vd += __shfl_down(vd, off, 32);
        }
        if (lane == 0) { as2[nn] = vs; ad2[nn] = vd; }
    }
}

// K8: layer-2 logits + segment max (one thread per edge, H=1)
__global__ void k_logits2(const int* __restrict__ ei, const float* __restrict__ ea,
                          const float* __restrict__ cst, const float* __restrict__ as2,
                          const float* __restrict__ ad2, float* __restrict__ lg2,
                          unsigned* __restrict__ m2, int E, int N) {
    int e = blockIdx.x * blockDim.x + threadIdx.x;
    if (e >= E + N) return;
    int s, d;
    float ae;
    if (e < E) {
        s = ei[e];
        d = ei[E + e];
        float sum = 0.f;
#pragma unroll
        for (int t = 0; t < 16; ++t) sum += ea[(size_t)e * 16 + t] * cst[80 + t];
        ae = sum;
    } else {
        s = d = e - E;
        ae = cst[100];
    }
    float v = as2[s] + ad2[d] + ae;
    v = (v > 0.f) ? v : NEG_SLOPE * v;
    lg2[e] = v;
    atomicMax(&m2[d], fenc(v));
}

__global__ void k_exps2(const int* __restrict__ ei, float* __restrict__ lg2,
                        const unsigned* __restrict__ m2, float* __restrict__ den2,
                        int E, int N) {
    int e = blockIdx.x * blockDim.x + threadIdx.x;
    if (e >= E + N) return;
    int d = (e < E) ? ei[E + e] : e - E;
    float ex = __expf(lg2[e] - fdec(m2[d]));
    lg2[e] = ex;
    atomicAdd(&den2[d], ex);
}

// K10: CSR aggregation layer 2 + bias — one wave per dst row; halves of the
// wave process even/odd edges, lanes<32 own the 32 channels.
__global__ void k_aggr2(const int* __restrict__ rowptr, const int* __restrict__ csr_src,
                        const int* __restrict__ csr_eid, const float* __restrict__ lg2,
                        const float* __restrict__ den2, const float* __restrict__ h2,
                        const float* __restrict__ b2, float* __restrict__ out, int N) {
    int wid = (blockIdx.x * blockDim.x + threadIdx.x) >> 6;
    int lane = threadIdx.x & 63;
    if (wid >= N) return;
    const int c = lane & 31;
    const int half = lane >> 5;
    const int start = rowptr[wid], end = rowptr[wid + 1];
    float acc = 0.f;
    for (int i = start + half; i < end; i += 2) {
        int s = csr_src[i], e = csr_eid[i];
        acc += lg2[e] * h2[(size_t)s * 32 + c];
    }
    acc += __shfl_down(acc, 32, 64);
    if (half == 0) {
        float inv = 1.f / (den2[wid] + 1e-16f);
        out[(size_t)wid * 32 + c] = acc * inv + b2[c];
    }
}

extern "C" void kernel_launch(void* const* d_in, const int* in_sizes, int n_in,
                              void* d_out, int out_size, void* d_ws, size_t ws_size,
                              hipStream_t stream) {
    const float* x    = (const float*)d_in[0];
    const int*   ei   = (const int*)d_in[1];
    const float* ea   = (const float*)d_in[2];
    const float* W1   = (const float*)d_in[3];
    const float* We1  = (const float*)d_in[4];
    const float* as1w = (const float*)d_in[5];
    const float* ad1w = (const float*)d_in[6];
    const float* ae1w = (const float*)d_in[7];
    const float* b1   = (const float*)d_in[8];
    const float* W2   = (const float*)d_in[9];
    const float* We2  = (const float*)d_in[10];
    const float* as2w = (const float*)d_in[11];
    const float* ad2w = (const float*)d_in[12];
    const float* ae2w = (const float*)d_in[13];
    const float* b2   = (const float*)d_in[14];

    const int N  = in_sizes[0] / 128;
    const int E  = in_sizes[2] / 16;
    const int E2 = E + N;
    const int NB = (N + 1023) / 1024;

    float* ws = (float*)d_ws;
    size_t o = 0;
    float* cst  = ws;       o += 128;
    float* h1   = ws + o;   o += (size_t)N * 128;   // layer-2 buffers overlay this later
    float* out1 = ws + o;   o += (size_t)N * 128;
    float* lg1  = ws + o;   o += (size_t)E2 * 4;
    float* as1  = ws + o;   o += (size_t)N * 4;
    float* ad1  = ws + o;   o += (size_t)N * 4;
    unsigned* m1 = (unsigned*)(ws + o); o += (size_t)N * 4;
    float* den1 = ws + o;   o += (size_t)N * 4;
    int* rowptr = (int*)(ws + o);  o += (size_t)N + 1;
    int* cursor = (int*)(ws + o);  o += (size_t)N;       // also deg
    int* csr_src = (int*)(ws + o); o += (size_t)E2;
    int* csr_eid = (int*)(ws + o); o += (size_t)E2;
    int* scan_excl = (int*)(ws + o); o += (size_t)N;
    int* scan_bsum = (int*)(ws + o); o += 1024;
    // overlay layer 2 onto h1 region (dead after gemm2 consumes out1)
    float* h2   = h1;
    float* as2  = h2 + (size_t)N * 32;
    float* ad2  = as2 + N;
    float* lg2  = ad2 + N;
    unsigned* m2 = (unsigned*)(lg2 + E2);
    float* den2 = (float*)m2 + N;

    // zero init: cst, m1+den1 (contiguous), cursor
    hipMemsetAsync(cst, 0, 128 * sizeof(float), stream);
    hipMemsetAsync(m1, 0, (size_t)N * 8 * sizeof(float), stream);
    hipMemsetAsync(cursor, 0, (size_t)N * sizeof(int), stream);

    // CSR build (independent of feature pipeline)
    k_deg<<<(E2 + 255) / 256, 256, 0, stream>>>(ei, cursor, E, N);
    k_scan1<<<NB, 1024, 0, stream>>>(cursor, scan_excl, scan_bsum, N);
    k_scan2<<<1, 1024, 0, stream>>>(scan_bsum, NB);
    k_scan3<<<(N + 255) / 256, 256, 0, stream>>>(scan_excl, scan_bsum, rowptr, cursor, N, E2);
    k_fill<<<(E2 + 255) / 256, 256, 0, stream>>>(ei, cursor, csr_src, csr_eid, E, N);

    k_edge_sum<<<256, 256, 0, stream>>>(ea, cst, E);
    k_prep<<<1, 128, 0, stream>>>(We1, ae1w, We2, ae2w, cst, (float)E);
    k_gemm1<<<(N + 3) / 4, 128, 0, stream>>>(x, W1, as1w, ad1w, h1, as1, ad1, N);

    int tot1 = E2 * 4;
    k_logits1<<<(tot1 + 255) / 256, 256, 0, stream>>>(ei, ea, cst, as1, ad1, lg1, m1, E, N);
    k_exps1<<<(tot1 + 255) / 256, 256, 0, stream>>>(ei, lg1, m1, den1, E, N);
    k_aggr1<<<(N + 3) / 4, 256, 0, stream>>>(rowptr, csr_src, csr_eid, lg1, den1, h1, out1, N);

    // zero m2+den2 (overlaid region was used during layer 1)
    hipMemsetAsync(m2, 0, (size_t)N * 2 * sizeof(float), stream);

    k_gemm2<<<(N + 7) / 8, 256, 0, stream>>>(out1, b1, W2, as2w, ad2w, h2, as2, ad2, N);
    k_logits2<<<(E2 + 255) / 256, 256, 0, stream>>>(ei, ea, cst, as2, ad2, lg2, m2, E, N);
    k_exps2<<<(E2 + 255) / 256, 256, 0, stream>>>(ei, lg2, m2, den2, E, N);
    k_aggr2<<<(N + 3) / 4, 256, 0, stream>>>(rowptr, csr_src, csr_eid, lg2, den2, h2, b2, (float*)d_out, N);
}

// Round 8
// 457.332 us; speedup vs baseline: 1.9373x; 1.3782x over previous
//
#include <hip/hip_runtime.h>

#define NEG_SLOPE 0.2f

// K0: fused dst-degree histogram + edge_attr column sums -> cursor, cst[0..16)
__global__ void k_pre(const int* __restrict__ ei, const float* __restrict__ ea,
                      int* __restrict__ cursor, float* __restrict__ cst, int E) {
    float loc[16];
#pragma unroll
    for (int d = 0; d < 16; ++d) loc[d] = 0.f;
    int stride = gridDim.x * blockDim.x;
    for (int e = blockIdx.x * blockDim.x + threadIdx.x; e < E; e += stride) {
        atomicAdd(&cursor[ei[E + e]], 1);
#pragma unroll
        for (int d = 0; d < 16; ++d) loc[d] += ea[(size_t)e * 16 + d];
    }
    __shared__ float sh[16];
    if (threadIdx.x < 16) sh[threadIdx.x] = 0.f;
    __syncthreads();
#pragma unroll
    for (int d = 0; d < 16; ++d) atomicAdd(&sh[d], loc[d]);
    __syncthreads();
    if (threadIdx.x < 16) atomicAdd(&cst[threadIdx.x], sh[threadIdx.x]);
}

// scan phase 1: block-local exclusive scan of (deg+1) [+1 = self-loop]
__global__ void k_scan1(const int* __restrict__ deg, int* __restrict__ excl,
                        int* __restrict__ bsum, int N) {
    __shared__ int sh[1024];
    const int t = threadIdx.x;
    const int i = blockIdx.x * 1024 + t;
    int v = (i < N) ? deg[i] + 1 : 0;
    sh[t] = v;
    __syncthreads();
    for (int off = 1; off < 1024; off <<= 1) {
        int add = (t >= off) ? sh[t - off] : 0;
        __syncthreads();
        sh[t] += add;
        __syncthreads();
    }
    if (i < N) excl[i] = sh[t] - v;
    if (t == 1023) bsum[blockIdx.x] = sh[1023];
}

// fused: block 0 = exclusive scan of bsum; block 1 = weight prep
// cst: [0..16) e_mean, [16..80) P1[d][h], [80..96) P2[d], [96..100) aloop1, [100] aloop2
__global__ void k_mid(int* __restrict__ bsum, int nb,
                      const float* __restrict__ We1, const float* __restrict__ ae1,
                      const float* __restrict__ We2, const float* __restrict__ ae2,
                      float* __restrict__ cst, float Ef) {
    __shared__ int sh[1024];
    const int t = threadIdx.x;
    if (blockIdx.x == 0) {
        int v = (t < nb) ? bsum[t] : 0;
        sh[t] = v;
        __syncthreads();
        for (int off = 1; off < 1024; off <<= 1) {
            int add = (t >= off) ? sh[t - off] : 0;
            __syncthreads();
            sh[t] += add;
            __syncthreads();
        }
        if (t < nb) bsum[t] = sh[t] - v;
    } else {
        if (t < 16) cst[t] = cst[t] / Ef;
        if (t < 64) {
            int d = t >> 2, h = t & 3;
            float s = 0.f;
            for (int c = 0; c < 32; ++c) s += We1[d * 128 + h * 32 + c] * ae1[h * 32 + c];
            cst[16 + t] = s;
        } else if (t < 80) {
            int d = t - 64;
            float s = 0.f;
            for (int c = 0; c < 32; ++c) s += We2[d * 32 + c] * ae2[c];
            cst[80 + d] = s;
        }
        __threadfence_block();
        __syncthreads();
        if (t < 4) {
            float s = 0.f;
            for (int d = 0; d < 16; ++d) s += cst[d] * cst[16 + d * 4 + t];
            cst[96 + t] = s;
        } else if (t == 4) {
            float s = 0.f;
            for (int d = 0; d < 16; ++d) s += cst[d] * cst[80 + d];
            cst[100] = s;
        }
    }
}

// scan phase 3: rowptr[i] = cursor[i] = excl[i] + bsum[i>>10]; rowptr[N] = E2
__global__ void k_scan3(const int* __restrict__ excl, const int* __restrict__ bsum,
                        int* __restrict__ rowptr, int* __restrict__ cursor,
                        int N, int E2) {
    int i = blockIdx.x * blockDim.x + threadIdx.x;
    if (i < N) {
        int r = excl[i] + bsum[i >> 10];
        rowptr[i] = r;
        cursor[i] = r;
    }
    if (i == 0) rowptr[N] = E2;
}

__global__ void k_fill(const int* __restrict__ ei, int* __restrict__ cursor,
                       int* __restrict__ csr_src, int* __restrict__ csr_eid, int E, int N) {
    int e = blockIdx.x * blockDim.x + threadIdx.x;
    if (e >= E + N) return;
    int s, d;
    if (e < E) { s = ei[e]; d = ei[E + e]; }
    else       { s = d = e - E; }
    int pos = atomicAdd(&cursor[d], 1);
    csr_src[pos] = s;
    csr_eid[pos] = e;
}

// K3: h1 = x @ W1 (N x 128 @ 128 x 128); fused as1/ad1 per-node reductions.
__global__ void k_gemm1(const float* __restrict__ x, const float* __restrict__ W1,
                        const float* __restrict__ aS, const float* __restrict__ aD,
                        float* __restrict__ h1, float* __restrict__ as1,
                        float* __restrict__ ad1, int N) {
    __shared__ float xs[4][128];
    __shared__ float red[128];
    const int j = threadIdx.x;
    const int n0 = blockIdx.x * 4;
#pragma unroll
    for (int r = 0; r < 4; ++r) {
        int nn = n0 + r;
        xs[r][j] = (nn < N) ? x[(size_t)nn * 128 + j] : 0.f;
    }
    __syncthreads();
    float acc[4] = {0.f, 0.f, 0.f, 0.f};
    for (int k = 0; k < 128; ++k) {
        float w = W1[k * 128 + j];
        acc[0] += xs[0][k] * w;
        acc[1] += xs[1][k] * w;
        acc[2] += xs[2][k] * w;
        acc[3] += xs[3][k] * w;
    }
    float asw = aS[j], adw = aD[j];
    for (int r = 0; r < 4; ++r) {
        int nn = n0 + r;
        if (nn < N) {
            h1[(size_t)nn * 128 + j] = acc[r];
            red[j] = acc[r] * asw;
            __syncthreads();
            if (j < 4) {
                float s = 0.f;
                for (int c = 0; c < 32; ++c) s += red[j * 32 + c];
                as1[nn * 4 + j] = s;
            }
            __syncthreads();
            red[j] = acc[r] * adw;
            __syncthreads();
            if (j < 4) {
                float s = 0.f;
                for (int c = 0; c < 32; ++c) s += red[j * 32 + c];
                ad1[nn * 4 + j] = s;
            }
            __syncthreads();
        }
    }
}

// K6: FUSED layer-1 edge-softmax + aggregation. One wave per dst row.
// Phase 1: lane l computes ex[h] for edge start+l (no max shift: logits bounded,
// softmax shift-invariant). Phase 2: broadcast via wave-private LDS, gather h1.
__global__ void k_aggr1(const int* __restrict__ rowptr, const int* __restrict__ csr_src,
                        const int* __restrict__ csr_eid, const float* __restrict__ ea,
                        const float* __restrict__ cst, const float* __restrict__ as1,
                        const float* __restrict__ ad1, const float* __restrict__ h1,
                        float* __restrict__ out1, int N, int E) {
    __shared__ float lds_ex[4][4][64];
    __shared__ int   lds_ss[4][64];
    const int w = threadIdx.x >> 6;
    const int wid = (blockIdx.x * blockDim.x + threadIdx.x) >> 6;
    const int lane = threadIdx.x & 63;
    if (wid >= N) return;
    const int h = lane >> 4;                 // head owning channels 2*lane, 2*lane+1
    const int start = rowptr[wid], end = rowptr[wid + 1];
    const float adv0 = ad1[wid * 4 + 0], adv1 = ad1[wid * 4 + 1];
    const float adv2 = ad1[wid * 4 + 2], adv3 = ad1[wid * 4 + 3];
    float ax = 0.f, ay = 0.f, den = 0.f;
    for (int base = start; base < end; base += 64) {
        const int cnt = min(64, end - base);
        float e0 = 0.f, e1 = 0.f, e2 = 0.f, e3 = 0.f;
        int ssr = 0;
        if (lane < cnt) {
            int ee = csr_eid[base + lane];
            ssr = csr_src[base + lane];
            float d0, d1, d2, d3;
            if (ee < E) {
                d0 = d1 = d2 = d3 = 0.f;
                const float4* eav = (const float4*)&ea[(size_t)ee * 16];
#pragma unroll
                for (int q = 0; q < 4; ++q) {
                    float4 a = eav[q];
                    d0 += a.x * cst[16 + (q * 4 + 0) * 4 + 0] + a.y * cst[16 + (q * 4 + 1) * 4 + 0]
                        + a.z * cst[16 + (q * 4 + 2) * 4 + 0] + a.w * cst[16 + (q * 4 + 3) * 4 + 0];
                    d1 += a.x * cst[16 + (q * 4 + 0) * 4 + 1] + a.y * cst[16 + (q * 4 + 1) * 4 + 1]
                        + a.z * cst[16 + (q * 4 + 2) * 4 + 1] + a.w * cst[16 + (q * 4 + 3) * 4 + 1];
                    d2 += a.x * cst[16 + (q * 4 + 0) * 4 + 2] + a.y * cst[16 + (q * 4 + 1) * 4 + 2]
                        + a.z * cst[16 + (q * 4 + 2) * 4 + 2] + a.w * cst[16 + (q * 4 + 3) * 4 + 2];
                    d3 += a.x * cst[16 + (q * 4 + 0) * 4 + 3] + a.y * cst[16 + (q * 4 + 1) * 4 + 3]
                        + a.z * cst[16 + (q * 4 + 2) * 4 + 3] + a.w * cst[16 + (q * 4 + 3) * 4 + 3];
                }
            } else { d0 = cst[96]; d1 = cst[97]; d2 = cst[98]; d3 = cst[99]; }
            float v0 = as1[ssr * 4 + 0] + adv0 + d0;
            float v1 = as1[ssr * 4 + 1] + adv1 + d1;
            float v2 = as1[ssr * 4 + 2] + adv2 + d2;
            float v3 = as1[ssr * 4 + 3] + adv3 + d3;
            v0 = v0 > 0.f ? v0 : NEG_SLOPE * v0;
            v1 = v1 > 0.f ? v1 : NEG_SLOPE * v1;
            v2 = v2 > 0.f ? v2 : NEG_SLOPE * v2;
            v3 = v3 > 0.f ? v3 : NEG_SLOPE * v3;
            e0 = __expf(v0); e1 = __expf(v1); e2 = __expf(v2); e3 = __expf(v3);
        }
        lds_ex[w][0][lane] = e0;
        lds_ex[w][1][lane] = e1;
        lds_ex[w][2][lane] = e2;
        lds_ex[w][3][lane] = e3;
        lds_ss[w][lane] = ssr;
        for (int i = 0; i < cnt; ++i) {
            float exm = lds_ex[w][h][i];        // broadcast within 16-lane group
            int ss = lds_ss[w][i];
            float2 v = *(const float2*)&h1[(size_t)ss * 128 + 2 * lane];
            ax += exm * v.x;
            ay += exm * v.y;
            den += exm;
        }
    }
    const float inv = 1.f / (den + 1e-16f);
    float2 r; r.x = ax * inv; r.y = ay * inv;
    *(float2*)&out1[(size_t)wid * 128 + 2 * lane] = r;
}

// K7: h2 = relu(out1 + b1) @ W2 (N x 128 @ 128 x 32); fused as2/ad2.
__global__ void k_gemm2(const float* __restrict__ out1, const float* __restrict__ b1,
                        const float* __restrict__ W2, const float* __restrict__ aS,
                        const float* __restrict__ aD, float* __restrict__ h2,
                        float* __restrict__ as2, float* __restrict__ ad2, int N) {
    __shared__ float xs[8][128];
    const int lane = threadIdx.x & 31;
    const int r = threadIdx.x >> 5;
    const int nn = blockIdx.x * 8 + r;
    if (nn < N) {
#pragma unroll
        for (int t = 0; t < 4; ++t) {
            int k = t * 32 + lane;
            xs[r][k] = fmaxf(out1[(size_t)nn * 128 + k] + b1[k], 0.f);
        }
    }
    __syncthreads();
    if (nn < N) {
        float acc = 0.f;
        for (int k = 0; k < 128; ++k) acc += xs[r][k] * W2[k * 32 + lane];
        h2[(size_t)nn * 32 + lane] = acc;
        float vs = acc * aS[lane], vd = acc * aD[lane];
        for (int off = 16; off; off >>= 1) {
            vs += __shfl_down(vs, off, 32);
            vd += __shfl_down(vd, off, 32);
        }
        if (lane == 0) { as2[nn] = vs; ad2[nn] = vd; }
    }
}

// K10: FUSED layer-2 edge-softmax + aggregation + bias. One wave per dst row.
__global__ void k_aggr2(const int* __restrict__ rowptr, const int* __restrict__ csr_src,
                        const int* __restrict__ csr_eid, const float* __restrict__ ea,
                        const float* __restrict__ cst, const float* __restrict__ as2,
                        const float* __restrict__ ad2, const float* __restrict__ h2,
                        const float* __restrict__ b2, float* __restrict__ out, int N, int E) {
    __shared__ float lds_ex[4][64];
    __shared__ int   lds_ss[4][64];
    const int w = threadIdx.x >> 6;
    const int wid = (blockIdx.x * blockDim.x + threadIdx.x) >> 6;
    const int lane = threadIdx.x & 63;
    if (wid >= N) return;
    const int c = lane & 31;
    const int half = lane >> 5;
    const int start = rowptr[wid], end = rowptr[wid + 1];
    const float adv = ad2[wid];
    float acc = 0.f, den = 0.f;
    for (int base = start; base < end; base += 64) {
        const int cnt = min(64, end - base);
        float ex = 0.f;
        int ssr = 0;
        if (lane < cnt) {
            int ee = csr_eid[base + lane];
            ssr = csr_src[base + lane];
            float dd;
            if (ee < E) {
                dd = 0.f;
                const float4* eav = (const float4*)&ea[(size_t)ee * 16];
#pragma unroll
                for (int q = 0; q < 4; ++q) {
                    float4 a = eav[q];
                    dd += a.x * cst[80 + q * 4 + 0] + a.y * cst[80 + q * 4 + 1]
                        + a.z * cst[80 + q * 4 + 2] + a.w * cst[80 + q * 4 + 3];
                }
            } else { dd = cst[100]; }
            float v = as2[ssr] + adv + dd;
            v = v > 0.f ? v : NEG_SLOPE * v;
            ex = __expf(v);
        }
        lds_ex[w][lane] = ex;
        lds_ss[w][lane] = ssr;
        for (int i = half; i < cnt; i += 2) {
            float exm = lds_ex[w][i];
            int ss = lds_ss[w][i];
            acc += exm * h2[(size_t)ss * 32 + c];
            den += exm;
        }
    }
    den += __shfl_xor(den, 32, 64);          // both halves -> total denominator
    acc += __shfl_down(acc, 32, 64);
    if (half == 0) {
        float inv = 1.f / (den + 1e-16f);
        out[(size_t)wid * 32 + c] = acc * inv + b2[c];
    }
}

extern "C" void kernel_launch(void* const* d_in, const int* in_sizes, int n_in,
                              void* d_out, int out_size, void* d_ws, size_t ws_size,
                              hipStream_t stream) {
    const float* x    = (const float*)d_in[0];
    const int*   ei   = (const int*)d_in[1];
    const float* ea   = (const float*)d_in[2];
    const float* W1   = (const float*)d_in[3];
    const float* We1  = (const float*)d_in[4];
    const float* as1w = (const float*)d_in[5];
    const float* ad1w = (const float*)d_in[6];
    const float* ae1w = (const float*)d_in[7];
    const float* b1   = (const float*)d_in[8];
    const float* W2   = (const float*)d_in[9];
    const float* We2  = (const float*)d_in[10];
    const float* as2w = (const float*)d_in[11];
    const float* ad2w = (const float*)d_in[12];
    const float* ae2w = (const float*)d_in[13];
    const float* b2   = (const float*)d_in[14];

    const int N  = in_sizes[0] / 128;
    const int E  = in_sizes[2] / 16;
    const int E2 = E + N;
    const int NB = (N + 1023) / 1024;

    float* ws = (float*)d_ws;
    size_t o = 0;
    float* cst  = ws;       o += 128;
    int* cursor = (int*)(ws + o);  o += (size_t)N;       // deg, then fill cursor
    float* h1   = ws + o;   o += (size_t)N * 128;        // layer-2 overlays later
    float* out1 = ws + o;   o += (size_t)N * 128;
    float* as1  = ws + o;   o += (size_t)N * 4;
    float* ad1  = ws + o;   o += (size_t)N * 4;
    int* rowptr = (int*)(ws + o);  o += (size_t)N + 1;
    int* csr_src = (int*)(ws + o); o += (size_t)E2;
    int* csr_eid = (int*)(ws + o); o += (size_t)E2;
    int* scan_excl = (int*)(ws + o); o += (size_t)N;
    int* scan_bsum = (int*)(ws + o); o += 1024;
    // overlay layer 2 onto h1 region (h1 dead after k_aggr1)
    float* h2   = h1;
    float* as2  = h2 + (size_t)N * 32;
    float* ad2  = as2 + N;

    // single contiguous zero init: cst + cursor
    hipMemsetAsync(cst, 0, (128 + (size_t)N) * sizeof(float), stream);

    k_pre<<<256, 256, 0, stream>>>(ei, ea, cursor, cst, E);
    k_scan1<<<NB, 1024, 0, stream>>>(cursor, scan_excl, scan_bsum, N);
    k_mid<<<2, 1024, 0, stream>>>(scan_bsum, NB, We1, ae1w, We2, ae2w, cst, (float)E);
    k_scan3<<<(N + 255) / 256, 256, 0, stream>>>(scan_excl, scan_bsum, rowptr, cursor, N, E2);
    k_fill<<<(E2 + 255) / 256, 256, 0, stream>>>(ei, cursor, csr_src, csr_eid, E, N);

    k_gemm1<<<(N + 3) / 4, 128, 0, stream>>>(x, W1, as1w, ad1w, h1, as1, ad1, N);
    k_aggr1<<<(N + 3) / 4, 256, 0, stream>>>(rowptr, csr_src, csr_eid, ea, cst,
                                             as1, ad1, h1, out1, N, E);
    k_gemm2<<<(N + 7) / 8, 256, 0, stream>>>(out1, b1, W2, as2w, ad2w, h2, as2, ad2, N);
    k_aggr2<<<(N + 3) / 4, 256, 0, stream>>>(rowptr, csr_src, csr_eid, ea, cst,
                                             as2, ad2, h2, b2, (float*)d_out, N, E);
}

// Round 11
// 424.591 us; speedup vs baseline: 2.0867x; 1.0771x over previous
//
#include <hip/hip_runtime.h>

#define NEG_SLOPE 0.2f

// round-to-nearest-even fp32 -> bf16 bits
static __device__ __forceinline__ unsigned short f2bf(float f) {
    unsigned u = __float_as_uint(f);
    u += 0x7fffu + ((u >> 16) & 1u);
    return (unsigned short)(u >> 16);
}

// K-1: weight prep (no data deps): P1[d][h] at cst[16..80), P2[d] at cst[80..96)
__global__ void k_prep0(const float* __restrict__ We1, const float* __restrict__ ae1,
                        const float* __restrict__ We2, const float* __restrict__ ae2,
                        float* __restrict__ cst) {
    int t = threadIdx.x;
    if (t < 64) {
        int d = t >> 2, h = t & 3;
        float s = 0.f;
        for (int c = 0; c < 32; ++c) s += We1[d * 128 + h * 32 + c] * ae1[h * 32 + c];
        cst[16 + t] = s;
    } else if (t < 80) {
        int d = t - 64;
        float s = 0.f;
        for (int c = 0; c < 32; ++c) s += We2[d * 32 + c] * ae2[c];
        cst[80 + d] = s;
    }
}

// K0: fused dst-degree histogram + edge_attr column sums + SEQUENTIAL edge-dot
// precompute: edot1[e] = ea[e]·P1 (4 heads), edot2[e] = ea[e]·P2.
__global__ void k_pre(const int* __restrict__ ei, const float* __restrict__ ea,
                      int* __restrict__ cursor, float* __restrict__ cst,
                      float4* __restrict__ edot1, float* __restrict__ edot2, int E) {
    float loc[16];
#pragma unroll
    for (int d = 0; d < 16; ++d) loc[d] = 0.f;
    int stride = gridDim.x * blockDim.x;
    for (int e = blockIdx.x * blockDim.x + threadIdx.x; e < E; e += stride) {
        atomicAdd(&cursor[ei[E + e]], 1);
        const float4* eav = (const float4*)&ea[(size_t)e * 16];
        float d0 = 0.f, d1 = 0.f, d2 = 0.f, d3 = 0.f, dd = 0.f;
#pragma unroll
        for (int q = 0; q < 4; ++q) {
            float4 a = eav[q];
            loc[q * 4 + 0] += a.x; loc[q * 4 + 1] += a.y;
            loc[q * 4 + 2] += a.z; loc[q * 4 + 3] += a.w;
            d0 += a.x * cst[16 + (q * 4 + 0) * 4 + 0] + a.y * cst[16 + (q * 4 + 1) * 4 + 0]
                + a.z * cst[16 + (q * 4 + 2) * 4 + 0] + a.w * cst[16 + (q * 4 + 3) * 4 + 0];
            d1 += a.x * cst[16 + (q * 4 + 0) * 4 + 1] + a.y * cst[16 + (q * 4 + 1) * 4 + 1]
                + a.z * cst[16 + (q * 4 + 2) * 4 + 1] + a.w * cst[16 + (q * 4 + 3) * 4 + 1];
            d2 += a.x * cst[16 + (q * 4 + 0) * 4 + 2] + a.y * cst[16 + (q * 4 + 1) * 4 + 2]
                + a.z * cst[16 + (q * 4 + 2) * 4 + 2] + a.w * cst[16 + (q * 4 + 3) * 4 + 2];
            d3 += a.x * cst[16 + (q * 4 + 0) * 4 + 3] + a.y * cst[16 + (q * 4 + 1) * 4 + 3]
                + a.z * cst[16 + (q * 4 + 2) * 4 + 3] + a.w * cst[16 + (q * 4 + 3) * 4 + 3];
            dd += a.x * cst[80 + q * 4 + 0] + a.y * cst[80 + q * 4 + 1]
                + a.z * cst[80 + q * 4 + 2] + a.w * cst[80 + q * 4 + 3];
        }
        edot1[e] = make_float4(d0, d1, d2, d3);
        edot2[e] = dd;
    }
    __shared__ float sh[16];
    if (threadIdx.x < 16) sh[threadIdx.x] = 0.f;
    __syncthreads();
#pragma unroll
    for (int d = 0; d < 16; ++d) atomicAdd(&sh[d], loc[d]);
    __syncthreads();
    if (threadIdx.x < 16) atomicAdd(&cst[threadIdx.x], sh[threadIdx.x]);
}

// scan phase 1: block-local exclusive scan of (deg+1) [+1 = self-loop]
__global__ void k_scan1(const int* __restrict__ deg, int* __restrict__ excl,
                        int* __restrict__ bsum, int N) {
    __shared__ int sh[1024];
    const int t = threadIdx.x;
    const int i = blockIdx.x * 1024 + t;
    int v = (i < N) ? deg[i] + 1 : 0;
    sh[t] = v;
    __syncthreads();
    for (int off = 1; off < 1024; off <<= 1) {
        int add = (t >= off) ? sh[t - off] : 0;
        __syncthreads();
        sh[t] += add;
        __syncthreads();
    }
    if (i < N) excl[i] = sh[t] - v;
    if (t == 1023) bsum[blockIdx.x] = sh[1023];
}

// fused: block 0 = exclusive scan of bsum; block 1 = e_mean + self-loop dots
// cst: [0..16) e_mean, [16..80) P1, [80..96) P2, [96..100) aloop1, [100] aloop2
__global__ void k_mid(int* __restrict__ bsum, int nb, float* __restrict__ cst, float Ef) {
    __shared__ int sh[1024];
    const int t = threadIdx.x;
    if (blockIdx.x == 0) {
        int v = (t < nb) ? bsum[t] : 0;
        sh[t] = v;
        __syncthreads();
        for (int off = 1; off < 1024; off <<= 1) {
            int add = (t >= off) ? sh[t - off] : 0;
            __syncthreads();
            sh[t] += add;
            __syncthreads();
        }
        if (t < nb) bsum[t] = sh[t] - v;
    } else {
        if (t < 16) cst[t] = cst[t] / Ef;
        __threadfence_block();
        __syncthreads();
        if (t < 4) {
            float s = 0.f;
            for (int d = 0; d < 16; ++d) s += cst[d] * cst[16 + d * 4 + t];
            cst[96 + t] = s;
        } else if (t == 4) {
            float s = 0.f;
            for (int d = 0; d < 16; ++d) s += cst[d] * cst[80 + d];
            cst[100] = s;
        }
    }
}

// scan phase 3: rowptr/cursor from hierarchical scan; fill self-loop edot entries.
__global__ void k_scan3(const int* __restrict__ excl, const int* __restrict__ bsum,
                        int* __restrict__ rowptr, int* __restrict__ cursor,
                        const float* __restrict__ cst, float4* __restrict__ edot1,
                        float* __restrict__ edot2, int N, int E, int E2) {
    int i = blockIdx.x * blockDim.x + threadIdx.x;
    if (i < N) {
        int r = excl[i] + bsum[i >> 10];
        rowptr[i] = r;
        cursor[i] = r;
        edot1[E + i] = make_float4(cst[96], cst[97], cst[98], cst[99]);
        edot2[E + i] = cst[100];
    }
    if (i == 0) rowptr[N] = E2;
}

__global__ void k_fill(const int* __restrict__ ei, int* __restrict__ cursor,
                       int* __restrict__ csr_src, int* __restrict__ csr_eid, int E, int N) {
    int e = blockIdx.x * blockDim.x + threadIdx.x;
    if (e >= E + N) return;
    int s, d;
    if (e < E) { s = ei[e]; d = ei[E + e]; }
    else       { s = d = e - E; }
    int pos = atomicAdd(&cursor[d], 1);
    csr_src[pos] = s;
    csr_eid[pos] = e;
}

// K3: h1 = x @ W1 (N x 128 @ 128 x 128), stored as bf16; fused as1/ad1.
__global__ void k_gemm1(const float* __restrict__ x, const float* __restrict__ W1,
                        const float* __restrict__ aS, const float* __restrict__ aD,
                        unsigned short* __restrict__ h1b, float* __restrict__ as1,
                        float* __restrict__ ad1, int N) {
    __shared__ float xs[4][128];
    __shared__ float red[128];
    const int j = threadIdx.x;
    const int n0 = blockIdx.x * 4;
#pragma unroll
    for (int r = 0; r < 4; ++r) {
        int nn = n0 + r;
        xs[r][j] = (nn < N) ? x[(size_t)nn * 128 + j] : 0.f;
    }
    __syncthreads();
    float acc[4] = {0.f, 0.f, 0.f, 0.f};
    for (int k = 0; k < 128; ++k) {
        float w = W1[k * 128 + j];
        acc[0] += xs[0][k] * w;
        acc[1] += xs[1][k] * w;
        acc[2] += xs[2][k] * w;
        acc[3] += xs[3][k] * w;
    }
    float asw = aS[j], adw = aD[j];
    for (int r = 0; r < 4; ++r) {
        int nn = n0 + r;
        if (nn < N) {
            h1b[(size_t)nn * 128 + j] = f2bf(acc[r]);
            red[j] = acc[r] * asw;
            __syncthreads();
            if (j < 4) {
                float s = 0.f;
                for (int c = 0; c < 32; ++c) s += red[j * 32 + c];
                as1[nn * 4 + j] = s;
            }
            __syncthreads();
            red[j] = acc[r] * adw;
            __syncthreads();
            if (j < 4) {
                float s = 0.f;
                for (int c = 0; c < 32; ++c) s += red[j * 32 + c];
                ad1[nn * 4 + j] = s;
            }
            __syncthreads();
        }
    }
}

// K6: FUSED layer-1 edge-softmax + aggregation. One wave per dst row.
// bf16 h1 gather (4 B/lane), edot1 gather (16 B, mostly L2), float4 LDS broadcast.
__global__ void k_aggr1(const int* __restrict__ rowptr, const int* __restrict__ csr_src,
                        const int* __restrict__ csr_eid, const float4* __restrict__ edot1,
                        const float* __restrict__ as1, const float* __restrict__ ad1,
                        const unsigned int* __restrict__ h1u,
                        float* __restrict__ out1, int N) {
    __shared__ float4 lds_ex4[4][64];
    __shared__ int    lds_ss[4][64];
    const int w = threadIdx.x >> 6;
    const int wid = (blockIdx.x * blockDim.x + threadIdx.x) >> 6;
    const int lane = threadIdx.x & 63;
    if (wid >= N) return;
    const int h = lane >> 4;                 // head owning channels 2*lane, 2*lane+1
    const int start = rowptr[wid], end = rowptr[wid + 1];
    const float adv0 = ad1[wid * 4 + 0], adv1 = ad1[wid * 4 + 1];
    const float adv2 = ad1[wid * 4 + 2], adv3 = ad1[wid * 4 + 3];
    float ax = 0.f, ay = 0.f, den = 0.f;
    for (int base = start; base < end; base += 64) {
        const int cnt = min(64, end - base);
        float e0 = 0.f, e1 = 0.f, e2 = 0.f, e3 = 0.f;
        int ssr = 0;
        if (lane < cnt) {
            int ee = csr_eid[base + lane];
            ssr = csr_src[base + lane];
            float4 d = edot1[ee];
            float v0 = as1[ssr * 4 + 0] + adv0 + d.x;
            float v1 = as1[ssr * 4 + 1] + adv1 + d.y;
            float v2 = as1[ssr * 4 + 2] + adv2 + d.z;
            float v3 = as1[ssr * 4 + 3] + adv3 + d.w;
            v0 = v0 > 0.f ? v0 : NEG_SLOPE * v0;
            v1 = v1 > 0.f ? v1 : NEG_SLOPE * v1;
            v2 = v2 > 0.f ? v2 : NEG_SLOPE * v2;
            v3 = v3 > 0.f ? v3 : NEG_SLOPE * v3;
            e0 = __expf(v0); e1 = __expf(v1); e2 = __expf(v2); e3 = __expf(v3);
        }
        lds_ex4[w][lane] = make_float4(e0, e1, e2, e3);
        lds_ss[w][lane] = ssr;
        for (int i = 0; i < cnt; ++i) {
            float exm = ((const float*)&lds_ex4[w][i])[h];   // 4 banks, broadcast in group
            int ss = lds_ss[w][i];
            unsigned int v = h1u[(size_t)ss * 64 + lane];
            ax += exm * __uint_as_float(v << 16);            // channel 2*lane
            ay += exm * __uint_as_float(v & 0xffff0000u);    // channel 2*lane+1
            den += exm;
        }
    }
    const float inv = 1.f / (den + 1e-16f);
    float2 r; r.x = ax * inv; r.y = ay * inv;
    *(float2*)&out1[(size_t)wid * 128 + 2 * lane] = r;
}

// K7: h2 = relu(out1 + b1) @ W2 (N x 128 @ 128 x 32); fused as2/ad2. h2 stays fp32.
__global__ void k_gemm2(const float* __restrict__ out1, const float* __restrict__ b1,
                        const float* __restrict__ W2, const float* __restrict__ aS,
                        const float* __restrict__ aD, float* __restrict__ h2,
                        float* __restrict__ as2, float* __restrict__ ad2, int N) {
    __shared__ float xs[8][128];
    const int lane = threadIdx.x & 31;
    const int r = threadIdx.x >> 5;
    const int nn = blockIdx.x * 8 + r;
    if (nn < N) {
#pragma unroll
        for (int t = 0; t < 4; ++t) {
            int k = t * 32 + lane;
            xs[r][k] = fmaxf(out1[(size_t)nn * 128 + k] + b1[k], 0.f);
        }
    }
    __syncthreads();
    if (nn < N) {
        float acc = 0.f;
        for (int k = 0; k < 128; ++k) acc += xs[r][k] * W2[k * 32 + lane];
        h2[(size_t)nn * 32 + lane] = acc;
        float vs = acc * aS[lane], vd = acc * aD[lane];
        for (int off = 16; off; off >>= 1) {
            vs += __shfl_down(vs, off, 32);
            vd += __shfl_down(vd, off, 32);
        }
        if (lane == 0) { as2[nn] = vs; ad2[nn] = vd; }
    }
}

// K10: FUSED layer-2 edge-softmax + aggregation + bias. One wave per dst row.
__global__ void k_aggr2(const int* __restrict__ rowptr, const int* __restrict__ csr_src,
                        const int* __restrict__ csr_eid, const float* __restrict__ edot2,
                        const float* __restrict__ as2, const float* __restrict__ ad2,
                        const float* __restrict__ h2, const float* __restrict__ b2,
                        float* __restrict__ out, int N) {
    __shared__ float lds_ex[4][64];
    __shared__ int   lds_ss[4][64];
    const int w = threadIdx.x >> 6;
    const int wid = (blockIdx.x * blockDim.x + threadIdx.x) >> 6;
    const int lane = threadIdx.x & 63;
    if (wid >= N) return;
    const int c = lane & 31;
    const int half = lane >> 5;
    const int start = rowptr[wid], end = rowptr[wid + 1];
    const float adv = ad2[wid];
    float acc = 0.f, den = 0.f;
    for (int base = start; base < end; base += 64) {
        const int cnt = min(64, end - base);
        float ex = 0.f;
        int ssr = 0;
        if (lane < cnt) {
            int ee = csr_eid[base + lane];
            ssr = csr_src[base + lane];
            float v = as2[ssr] + adv + edot2[ee];
            v = v > 0.f ? v : NEG_SLOPE * v;
            ex = __expf(v);
        }
        lds_ex[w][lane] = ex;
        lds_ss[w][lane] = ssr;
        for (int i = half; i < cnt; i += 2) {
            float exm = lds_ex[w][i];
            int ss = lds_ss[w][i];
            acc += exm * h2[(size_t)ss * 32 + c];
            den += exm;
        }
    }
    den += __shfl_xor(den, 32, 64);          // both halves -> total denominator
    acc += __shfl_down(acc, 32, 64);
    if (half == 0) {
        float inv = 1.f / (den + 1e-16f);
        out[(size_t)wid * 32 + c] = acc * inv + b2[c];
    }
}

extern "C" void kernel_launch(void* const* d_in, const int* in_sizes, int n_in,
                              void* d_out, int out_size, void* d_ws, size_t ws_size,
                              hipStream_t stream) {
    const float* x    = (const float*)d_in[0];
    const int*   ei   = (const int*)d_in[1];
    const float* ea   = (const float*)d_in[2];
    const float* W1   = (const float*)d_in[3];
    const float* We1  = (const float*)d_in[4];
    const float* as1w = (const float*)d_in[5];
    const float* ad1w = (const float*)d_in[6];
    const float* ae1w = (const float*)d_in[7];
    const float* b1   = (const float*)d_in[8];
    const float* W2   = (const float*)d_in[9];
    const float* We2  = (const float*)d_in[10];
    const float* as2w = (const float*)d_in[11];
    const float* ad2w = (const float*)d_in[12];
    const float* ae2w = (const float*)d_in[13];
    const float* b2   = (const float*)d_in[14];

    const int N  = in_sizes[0] / 128;
    const int E  = in_sizes[2] / 16;
    const int E2 = E + N;
    const int NB = (N + 1023) / 1024;

    float* ws = (float*)d_ws;
    size_t o = 0;
    float* cst  = ws;       o += 128;
    int* cursor = (int*)(ws + o);  o += (size_t)N;       // deg, then fill cursor
    unsigned short* h1b = (unsigned short*)(ws + o); o += (size_t)N * 64; // bf16 [N][128]; layer-2 overlays
    float* out1 = ws + o;   o += (size_t)N * 128;
    float* as1  = ws + o;   o += (size_t)N * 4;
    float* ad1  = ws + o;   o += (size_t)N * 4;
    int* rowptr = (int*)(ws + o);  o += (size_t)N + 1;
    int* csr_src = (int*)(ws + o); o += (size_t)E2;
    int* csr_eid = (int*)(ws + o); o += (size_t)E2;
    int* scan_excl = (int*)(ws + o); o += (size_t)N;
    int* scan_bsum = (int*)(ws + o); o += 1024;
    float4* edot1 = (float4*)(ws + o); o += (size_t)E2 * 4;
    float* edot2 = ws + o;  o += (size_t)E2;
    // overlay layer 2 onto h1 region (h1b dead after k_aggr1):
    // h1b region is N*64 floats-worth; h2(N*32)+as2(N)+ad2(N) = N*34 floats. fits.
    float* h2   = (float*)h1b;
    float* as2  = h2 + (size_t)N * 32;
    float* ad2  = as2 + N;

    // single contiguous zero init: cst + cursor
    hipMemsetAsync(cst, 0, (128 + (size_t)N) * sizeof(float), stream);

    k_prep0<<<1, 128, 0, stream>>>(We1, ae1w, We2, ae2w, cst);
    k_pre<<<256, 256, 0, stream>>>(ei, ea, cursor, cst, edot1, edot2, E);
    k_scan1<<<NB, 1024, 0, stream>>>(cursor, scan_excl, scan_bsum, N);
    k_mid<<<2, 1024, 0, stream>>>(scan_bsum, NB, cst, (float)E);
    k_scan3<<<(N + 255) / 256, 256, 0, stream>>>(scan_excl, scan_bsum, rowptr, cursor,
                                                 cst, edot1, edot2, N, E, E2);
    k_fill<<<(E2 + 255) / 256, 256, 0, stream>>>(ei, cursor, csr_src, csr_eid, E, N);

    k_gemm1<<<(N + 3) / 4, 128, 0, stream>>>(x, W1, as1w, ad1w, h1b, as1, ad1, N);
    k_aggr1<<<(N + 3) / 4, 256, 0, stream>>>(rowptr, csr_src, csr_eid, edot1,
                                             as1, ad1, (const unsigned int*)h1b, out1, N);
    k_gemm2<<<(N + 7) / 8, 256, 0, stream>>>(out1, b1, W2, as2w, ad2w, h2, as2, ad2, N);
    k_aggr2<<<(N + 3) / 4, 256, 0, stream>>>(rowptr, csr_src, csr_eid, edot2,
                                             as2, ad2, h2, b2, (float*)d_out, N);
}